// Round 3
// 5151.657 us; speedup vs baseline: 1.2188x; 1.2188x over previous
//
#include <hip/hip_runtime.h>
#include <hip/hip_bf16.h>

#define BB 256   // batch
#define SS 512   // seq len
#define II 128   // input size
#define HH 256   // hidden size

typedef __attribute__((ext_vector_type(8))) __bf16 bf16x8;
typedef __attribute__((ext_vector_type(4))) float f32x4;

__device__ __forceinline__ unsigned short f2bf(float f) {
    unsigned u = __float_as_uint(f);
    unsigned r = u + 0x7fffu + ((u >> 16) & 1u);
    return (unsigned short)(r >> 16);
}

// ---------------------------------------------------------------------------
// Weight repack (unchanged): fp32 [4H x K] -> bf16 MFMA B-fragment chains.
// Chain nblk = s*4 + nwv*2 + chain; chunk (nblk*nkc+kc)*64+L holds lane L's
// 8 contiguous k elems. Gate map per frag col c: chain0 c<8->i, c>=8->f;
// chain1 c<8->g, c>=8->o; unit = s*16 + nwv*8 + (c&7).
// ---------------------------------------------------------------------------
__global__ void pack_w_kernel(const float* __restrict__ Wih,
                              const float* __restrict__ Whh,
                              unsigned short* __restrict__ wp,
                              int Kin, int nkc) {
    int idx = blockIdx.x * blockDim.x + threadIdx.x;
    int total = 64 * nkc * 64;
    if (idx >= total) return;
    int nblk = idx / (nkc * 64);
    int rem  = idx % (nkc * 64);
    int kc = rem >> 6;
    int L  = rem & 63;
    int p  = nblk * 16 + (L & 15);
    int s  = p >> 6;
    int q6 = p & 63;
    int nw = q6 >> 5;
    int nb = (q6 >> 4) & 1;
    int c  = q6 & 15;
    int gam = nb * 2 + (c >> 3);            // 0:i 1:f 2:g 3:o
    int u   = s * 16 + nw * 8 + (c & 7);
    int srow = gam * HH + u;
    int k0 = kc * 32 + (L >> 4) * 8;
    unsigned short* dst = wp + (size_t)idx * 8;
    for (int j = 0; j < 8; ++j) {
        int k = k0 + j;
        float v = (k < Kin) ? Wih[(size_t)srow * Kin + k]
                            : Whh[(size_t)srow * HH + (k - Kin)];
        dst[j] = f2bf(v);
    }
}

__global__ void pack_bias_kernel(const float* bi0, const float* bh0,
                                 const float* bi1, const float* bh1,
                                 float* __restrict__ biasP) {
    int p = blockIdx.x * blockDim.x + threadIdx.x;
    if (p >= 2048) return;
    int layer = p >> 10;
    int pp = p & 1023;
    int s  = pp >> 6;
    int q6 = pp & 63;
    int nw = q6 >> 5;
    int nb = (q6 >> 4) & 1;
    int c  = q6 & 15;
    int gam = nb * 2 + (c >> 3);
    int u   = s * 16 + nw * 8 + (c & 7);
    int r = gam * HH + u;
    biasP[p] = layer ? (bi1[r] + bh1[r]) : (bi0[r] + bh0[r]);
}

__device__ __forceinline__ bool wait_flag(unsigned int* f) {
    long it = 0;
    while (__hip_atomic_load(f, __ATOMIC_RELAXED, __HIP_MEMORY_SCOPE_AGENT) < 16u) {
        __builtin_amdgcn_s_sleep(1);
        if (++it > 2000000l) return false;   // safety bailout: no hangs
    }
    return true;
}

// ---------------------------------------------------------------------------
// Persistent 2-layer LSTM. 256 WGs x 256 thr, 1 WG/CU.
// Coherence protocol R5 (RETURNING far-atomic publication — no per-step fence):
//   - producer: cross-WG h data published via relaxed agent atomic SWAPS
//     whose RESULT IS CONSUMED (asm use).  Rationale: the flag atomicAdd
//     protocol proves agent RMWs execute at the LLC; R4's failure (absmax
//     1.6e-2 sparse stale) showed NON-returning swaps get an EARLY vmcnt ack
//     (before reaching the LLC), so the flag add could overtake them in the
//     fabric.  A returning swap's vmcnt retires only when the result VGPR is
//     written, and the result comes from where the RMW executed (LLC) =>
//     vmcnt(0) at the barrier ⇒ data IS at the LLC before the flag add.
//   - ordering: __syncthreads() drains vmcnt(0) before tid0's flag atomicAdd.
//   - consumer: relaxed agent atomic loads only, NO acquire fence (R1 proved
//     correct; R2's acquire buffer_inv caused the 1.45 GB writeback storm).
//   - x/weights/bias normal cached loads; outY plain cached stores (flushed
//     by the end-of-kernel implicit release).
//   - R3 historical: plain relaxed/sc-bit stores + no fence => stale (they
//     linger in XCD L2); fence(release,agent) (buffer_wbl2) fixed it but cost
//     ~10 us/step (32 WGs/XCD serializing full-L2 walks) — that is the cost
//     this protocol removes.
// ---------------------------------------------------------------------------
template <int LAYER>
__device__ __forceinline__ void run_layer(
    int bid, const float* __restrict__ x,
    const unsigned short* __restrict__ wp,
    const float* __restrict__ biasP,
    unsigned short* __restrict__ Y0,
    unsigned short* __restrict__ Y1,
    unsigned int* __restrict__ flags,
    float* __restrict__ out,
    unsigned short* As, int* abort_flag) {

    constexpr int KIN = LAYER ? HH : II;
    constexpr int KC  = KIN + HH;        // 384 / 512
    constexpr int NKC = KC >> 5;         // 12 / 16
    constexpr int KCP = KC + 8;          // A-row stride offset: 8 shorts

    const int g = (bid >> 4) & 7;
    const int s = bid & 15;
    const int tid = threadIdx.x;
    const int L = tid & 63;
    const int w = tid >> 6;
    const int mw = w & 1;
    const int nwv = w >> 1;
    const int c = L & 15;
    const int b0 = g * 32;

    // ---- persistent weight fragments (VGPR/AGPR file) ----
    const unsigned short* wB0 = wp + ((size_t)((s * 4 + nwv * 2 + 0) * NKC) * 64 + L) * 8;
    const unsigned short* wB1 = wp + ((size_t)((s * 4 + nwv * 2 + 1) * NKC) * 64 + L) * 8;
    bf16x8 w0r[NKC], w1r[NKC];
#pragma unroll
    for (int kc = 0; kc < NKC; ++kc) {
        w0r[kc] = *(const bf16x8*)(wB0 + (size_t)kc * 512);
        w1r[kc] = *(const bf16x8*)(wB1 + (size_t)kc * 512);
    }
    const float bq0 = biasP[LAYER * 1024 + s * 64 + nwv * 32 + c];
    const float bq1 = biasP[LAYER * 1024 + s * 64 + nwv * 32 + 16 + c];

    float cst[4] = {0.f, 0.f, 0.f, 0.f};

    unsigned int* fl0 = flags;
    unsigned int* fl1 = flags + SS * 8;
    float* outY  = out;
    float* outHn = out + (size_t)BB * SS * HH;
    float* outCn = outHn + (size_t)BB * HH;
    unsigned long long* Y0l = (unsigned long long*)Y0;   // 64 u64 per 256-unit row
    unsigned long long* Y1l = (unsigned long long*)Y1;
    unsigned int* Y0u = (unsigned int*)Y0;
    unsigned int* Y1u = (unsigned int*)Y1;

    // staging geometry: one batch row per 8 threads, 8 x u64 per thread
    const int row8 = tid >> 3;        // 0..31
    const int c8   = tid & 7;         // u64 col base; cols c8 + 8j, j=0..7
    // x staging (layer0): float4 rows rowb+8k, col cc
    const int rowb = tid >> 5;
    const int cc   = tid & 31;

    int ahead0 = 0;                   // layer1: fl0 peek-ahead cache (flags monotone)

    for (int t = 0; t < SS; ++t) {
        unsigned long long yv[8];     // layer1: y0[t] staged regs
        float4 xv[4];                 // layer0: x[t]

        if (LAYER == 0) {
            // ---- prefetch x (no dependency) ----
#pragma unroll
            for (int k = 0; k < 4; ++k) {
                int row = rowb + 8 * k;
                xv[k] = *(const float4*)(x + ((size_t)(b0 + row) * SS + t) * II + cc * 4);
            }
            if (tid == 0 && t > 0) {
                if (!wait_flag(fl0 + (t - 1) * 8 + g)) *abort_flag = 1;
            }
            __syncthreads();
            if (*abort_flag) return;
        } else {
            // ---- gate on fl0[t] (usually pre-satisfied; peek-ahead) ----
            if (tid == 0 && t >= ahead0) {
                if (!wait_flag(fl0 + t * 8 + g)) *abort_flag = 1;
                int pt = t + 16; if (pt > SS - 1) pt = SS - 1;
                if (__hip_atomic_load(fl0 + pt * 8 + g, __ATOMIC_RELAXED,
                                      __HIP_MEMORY_SCOPE_AGENT) >= 16u)
                    ahead0 = pt + 1;
            }
            __syncthreads();
            if (*abort_flag) return;
            // ---- issue y0[t] loads; latency overlaps the fl1 poll ----
            {
                unsigned long long* sp = Y0l + ((size_t)t * BB + b0 + row8) * 64;
#pragma unroll
                for (int j = 0; j < 8; ++j)
                    yv[j] = __hip_atomic_load(sp + c8 + 8 * j, __ATOMIC_RELAXED,
                                              __HIP_MEMORY_SCOPE_AGENT);
            }
            if (tid == 0 && t > 0) {
                if (!wait_flag(fl1 + (t - 1) * 8 + g)) *abort_flag = 1;
            }
            __syncthreads();
            if (*abort_flag) return;
        }

        // ---- h_{t-1} gather (batched u64 agent atomics) ----
        unsigned long long hv[8];
        if (t > 0) {
            unsigned long long* sp = (LAYER == 0)
                ? Y0l + ((size_t)(t - 1) * BB + b0 + row8) * 64
                : Y1l + ((size_t)((t - 1) & 3) * BB + b0 + row8) * 64;
#pragma unroll
            for (int j = 0; j < 8; ++j)
                hv[j] = __hip_atomic_load(sp + c8 + 8 * j, __ATOMIC_RELAXED,
                                          __HIP_MEMORY_SCOPE_AGENT);
        } else {
#pragma unroll
            for (int j = 0; j < 8; ++j) hv[j] = 0ull;
        }

        // ---- write A = [input | h_prev] to LDS ----
        if (LAYER == 0) {
#pragma unroll
            for (int k = 0; k < 4; ++k) {
                int row = rowb + 8 * k;
                ushort4 pk;
                pk.x = f2bf(xv[k].x); pk.y = f2bf(xv[k].y);
                pk.z = f2bf(xv[k].z); pk.w = f2bf(xv[k].w);
                *(ushort4*)&As[row * KCP + cc * 4] = pk;
            }
        } else {
#pragma unroll
            for (int j = 0; j < 8; ++j)
                *(unsigned long long*)&As[row8 * KCP + (c8 + 8 * j) * 4] = yv[j];
        }
#pragma unroll
        for (int j = 0; j < 8; ++j)
            *(unsigned long long*)&As[row8 * KCP + KIN + (c8 + 8 * j) * 4] = hv[j];
        __syncthreads();

        // ---- GEMM: gates[32 x 64] = A[32 x KC] * W^T ----
        f32x4 acc0 = {0.f, 0.f, 0.f, 0.f};
        f32x4 acc1 = {0.f, 0.f, 0.f, 0.f};
        const unsigned short* aBase = &As[(mw * 16 + c) * KCP + (L >> 4) * 8];
#pragma unroll
        for (int kc = 0; kc < NKC; ++kc) {
            bf16x8 a = *(const bf16x8*)(aBase + kc * 32);
            acc0 = __builtin_amdgcn_mfma_f32_16x16x32_bf16(a, w0r[kc], acc0, 0, 0, 0);
            acc1 = __builtin_amdgcn_mfma_f32_16x16x32_bf16(a, w1r[kc], acc1, 0, 0, 0);
        }

        // ---- epilogue: acc0 = i|f, acc1 = g|o (partner lane L^8) ----
#pragma unroll
        for (int r = 0; r < 4; ++r) {
            float x0 = acc0[r] + bq0;
            float x1 = acc1[r] + bq1;
            float y0v = __shfl_xor(x0, 8, 64);
            float y1v = __shfl_xor(x1, 8, 64);
            bool lo = (L & 8) == 0;
            float iv = lo ? x0 : y0v;
            float fv = lo ? y0v : x0;
            float gv = lo ? x1 : y1v;
            float ov = lo ? y1v : x1;
            iv = 1.f / (1.f + __expf(-iv));
            fv = 1.f / (1.f + __expf(-fv));
            ov = 1.f / (1.f + __expf(-ov));
            gv = 1.f - 2.f / (1.f + __expf(2.f * gv));
            float cn = fv * cst[r] + iv * gv;
            cst[r] = cn;
            float tc = 1.f - 2.f / (1.f + __expf(2.f * cn));
            float hn = ov * tc;

            int brow = b0 + mw * 16 + ((L >> 4) << 2) + r;
            int hu = s * 16 + nwv * 8 + (L & 7);
            // pack 2 adjacent units (lane pair L, L^1) into one 4B RETURNING
            // far-atomic swap.  Result consumed by empty asm => compiler emits
            // the returning encoding; vmcnt retires only when the LLC sends
            // the old value back => at the barrier the data is LLC-visible.
            unsigned hb = (unsigned)f2bf(hn);
            unsigned pb = (unsigned)__shfl_xor((int)hb, 1, 64);
            unsigned packed = hb | (pb << 16);
            if (lo && (L & 1) == 0) {
                size_t di = (((size_t)(LAYER == 0 ? t * BB : (size_t)(t & 3) * BB)
                              + brow) * HH + hu) >> 1;
                unsigned old = __hip_atomic_exchange(
                    (LAYER == 0 ? Y0u : Y1u) + di, packed,
                    __ATOMIC_RELAXED, __HIP_MEMORY_SCOPE_AGENT);
                asm volatile("" :: "v"(old));   // keep returning form; no cost
            }
            if (LAYER == 1 && lo) {
                outY[((size_t)brow * SS + t) * HH + hu] = hn;
                if (t == SS - 1) {
                    outHn[brow * HH + hu] = hn;
                    outCn[brow * HH + hu] = cn;
                }
            }
        }

        __syncthreads();  // vmcnt(0): all returning swaps ack'd BY THE LLC
        if (tid == 0) {
            atomicAdd((LAYER ? fl1 : fl0) + t * 8 + g, 1u);
        }
    }
}

__global__ __launch_bounds__(256, 1) void lstm_main(
    const float* __restrict__ x,
    const unsigned short* __restrict__ wp0,
    const unsigned short* __restrict__ wp1,
    const float* __restrict__ biasP,
    unsigned short* __restrict__ Y0,
    unsigned short* __restrict__ Y1,
    unsigned int* __restrict__ flags,
    float* __restrict__ out) {

    __shared__ unsigned short As[32 * 520];
    __shared__ int abort_flag;
    if (threadIdx.x == 0) abort_flag = 0;

    int bid = blockIdx.x;
    if (bid < 128)
        run_layer<0>(bid, x, wp0, biasP, Y0, Y1, flags, out, As, &abort_flag);
    else
        run_layer<1>(bid, x, wp1, biasP, Y0, Y1, flags, out, As, &abort_flag);
}

extern "C" void kernel_launch(void* const* d_in, const int* in_sizes, int n_in,
                              void* d_out, int out_size, void* d_ws, size_t ws_size,
                              hipStream_t stream) {
    const float* x    = (const float*)d_in[0];
    const float* Wih0 = (const float*)d_in[1];
    const float* Whh0 = (const float*)d_in[2];
    const float* bih0 = (const float*)d_in[3];
    const float* bhh0 = (const float*)d_in[4];
    const float* Wih1 = (const float*)d_in[5];
    const float* Whh1 = (const float*)d_in[6];
    const float* bih1 = (const float*)d_in[7];
    const float* bhh1 = (const float*)d_in[8];

    char* ws = (char*)d_ws;
    size_t o = 0;
    unsigned short* wp0 = (unsigned short*)(ws + o); o += (size_t)64 * 12 * 512 * 2;  // 768 KB
    unsigned short* wp1 = (unsigned short*)(ws + o); o += (size_t)64 * 16 * 512 * 2;  // 1 MB
    float* biasP = (float*)(ws + o);                 o += 2048 * 4;
    unsigned short* Y0 = (unsigned short*)(ws + o);  o += (size_t)SS * BB * HH * 2;   // 67 MB
    unsigned short* Y1 = (unsigned short*)(ws + o);  o += (size_t)4 * BB * HH * 2;    // 512 KB
    unsigned int* flags = (unsigned int*)(ws + o);   o += (size_t)2 * SS * 8 * 4;     // 32 KB

    hipMemsetAsync(flags, 0, (size_t)2 * SS * 8 * 4, stream);
    pack_w_kernel<<<192, 256, 0, stream>>>(Wih0, Whh0, wp0, II, 12);
    pack_w_kernel<<<256, 256, 0, stream>>>(Wih1, Whh1, wp1, HH, 16);
    pack_bias_kernel<<<8, 256, 0, stream>>>(bih0, bhh0, bih1, bhh1, biasP);
    lstm_main<<<256, 256, 0, stream>>>(x, wp0, wp1, biasP, Y0, Y1, flags, (float*)d_out);
}

// Round 8
// 2868.020 us; speedup vs baseline: 2.1893x; 1.7962x over previous
//
#include <hip/hip_runtime.h>
#include <hip/hip_bf16.h>

#define BB 256   // batch
#define SS 512   // seq len
#define II 128   // input size
#define HH 256   // hidden size

typedef __attribute__((ext_vector_type(8))) __bf16 bf16x8;
typedef __attribute__((ext_vector_type(4))) float f32x4;

__device__ __forceinline__ unsigned short f2bf(float f) {
    unsigned u = __float_as_uint(f);
    unsigned r = u + 0x7fffu + ((u >> 16) & 1u);
    return (unsigned short)(r >> 16);
}

// ---------------------------------------------------------------------------
// Weight repack (unchanged): fp32 [4H x K] -> bf16 MFMA B-fragment chains.
// Chain nblk = s*4 + nwv*2 + chain; chunk (nblk*nkc+kc)*64+L holds lane L's
// 8 contiguous k elems. Gate map per frag col c: chain0 c<8->i, c>=8->f;
// chain1 c<8->g, c>=8->o; unit = s*16 + nwv*8 + (c&7).
// ---------------------------------------------------------------------------
__global__ void pack_w_kernel(const float* __restrict__ Wih,
                              const float* __restrict__ Whh,
                              unsigned short* __restrict__ wp,
                              int Kin, int nkc) {
    int idx = blockIdx.x * blockDim.x + threadIdx.x;
    int total = 64 * nkc * 64;
    if (idx >= total) return;
    int nblk = idx / (nkc * 64);
    int rem  = idx % (nkc * 64);
    int kc = rem >> 6;
    int L  = rem & 63;
    int p  = nblk * 16 + (L & 15);
    int s  = p >> 6;
    int q6 = p & 63;
    int nw = q6 >> 5;
    int nb = (q6 >> 4) & 1;
    int c  = q6 & 15;
    int gam = nb * 2 + (c >> 3);            // 0:i 1:f 2:g 3:o
    int u   = s * 16 + nw * 8 + (c & 7);
    int srow = gam * HH + u;
    int k0 = kc * 32 + (L >> 4) * 8;
    unsigned short* dst = wp + (size_t)idx * 8;
    for (int j = 0; j < 8; ++j) {
        int k = k0 + j;
        float v = (k < Kin) ? Wih[(size_t)srow * Kin + k]
                            : Whh[(size_t)srow * HH + (k - Kin)];
        dst[j] = f2bf(v);
    }
}

__global__ void pack_bias_kernel(const float* bi0, const float* bh0,
                                 const float* bi1, const float* bh1,
                                 float* __restrict__ biasP) {
    int p = blockIdx.x * blockDim.x + threadIdx.x;
    if (p >= 2048) return;
    int layer = p >> 10;
    int pp = p & 1023;
    int s  = pp >> 6;
    int q6 = pp & 63;
    int nw = q6 >> 5;
    int nb = (q6 >> 4) & 1;
    int c  = q6 & 15;
    int gam = nb * 2 + (c >> 3);
    int u   = s * 16 + nw * 8 + (c & 7);
    int r = gam * HH + u;
    biasP[p] = layer ? (bi1[r] + bh1[r]) : (bi0[r] + bh0[r]);
}

// ---------------------------------------------------------------------------
// Epoch-slot wait (R6): each (layer,group,slice) has its OWN 128B-padded slot
// holding the number of completed steps.  Wave 0 polls all 16 slots in
// parallel (lane L&15 -> slot L&15, 4-way duplicated across the wave) and
// exits when __all(v >= tgt).  vs the R5 shared counters: no RMW
// serialization (1 writer/line) and poll traffic spread over 16 lines/group
// instead of all 256 WGs hammering the SAME 64B line (8 groups x 4B flags
// shared one line => one LLC bank absorbed 256 RMWs + ~9k polls per step —
// the 25k-cycle/step mystery term).
// ---------------------------------------------------------------------------
__device__ __forceinline__ bool wait_slots(unsigned int* p, unsigned tgt) {
    long it = 0;
    for (;;) {
        unsigned v = __hip_atomic_load(p, __ATOMIC_RELAXED, __HIP_MEMORY_SCOPE_AGENT);
        if (__all((int)(v >= tgt))) return true;
        __builtin_amdgcn_s_sleep(1);
        if (++it > 2000000l) return false;   // safety bailout: no hangs
    }
}

// ---------------------------------------------------------------------------
// Persistent 2-layer LSTM. 256 WGs x 256 thr, 1 WG/CU.
// Coherence protocol R6 (returning far-atomic data + per-WG epoch slots):
//   - data publish: relaxed agent atomic SWAPS whose RESULT IS CONSUMED
//     (R5-proven: returning swap's vmcnt retires only when the LLC returns
//     the old value => vmcnt(0) at the barrier means data IS at the LLC).
//   - slot publish: after the drain barrier, tid0 returning-exchanges its
//     own slot to t+1.  Data-at-LLC happens-before slot issue => any
//     consumer that sees slot >= t+1 sees the data.
//   - consumer: relaxed agent atomic loads only, NO acquire fence (R1).
//   - NO per-step release fence (R5: removing the buffer_wbl2 walk).
// ---------------------------------------------------------------------------
template <int LAYER>
__device__ __forceinline__ void run_layer(
    int bid, const float* __restrict__ x,
    const unsigned short* __restrict__ wp,
    const float* __restrict__ biasP,
    unsigned short* __restrict__ Y0,
    unsigned short* __restrict__ Y1,
    unsigned int* __restrict__ slots,
    float* __restrict__ out,
    unsigned short* As, int* abort_flag) {

    constexpr int KIN = LAYER ? HH : II;
    constexpr int KC  = KIN + HH;        // 384 / 512
    constexpr int NKC = KC >> 5;         // 12 / 16
    constexpr int KCP = KC + 8;          // A-row stride offset: 8 shorts

    const int g = (bid >> 4) & 7;
    const int s = bid & 15;
    const int tid = threadIdx.x;
    const int L = tid & 63;
    const int w = tid >> 6;
    const int mw = w & 1;
    const int nwv = w >> 1;
    const int c = L & 15;
    const int b0 = g * 32;

    // ---- persistent weight fragments (VGPR/AGPR file) ----
    const unsigned short* wB0 = wp + ((size_t)((s * 4 + nwv * 2 + 0) * NKC) * 64 + L) * 8;
    const unsigned short* wB1 = wp + ((size_t)((s * 4 + nwv * 2 + 1) * NKC) * 64 + L) * 8;
    bf16x8 w0r[NKC], w1r[NKC];
#pragma unroll
    for (int kc = 0; kc < NKC; ++kc) {
        w0r[kc] = *(const bf16x8*)(wB0 + (size_t)kc * 512);
        w1r[kc] = *(const bf16x8*)(wB1 + (size_t)kc * 512);
    }
    const float bq0 = biasP[LAYER * 1024 + s * 64 + nwv * 32 + c];
    const float bq1 = biasP[LAYER * 1024 + s * 64 + nwv * 32 + 16 + c];

    float cst[4] = {0.f, 0.f, 0.f, 0.f};

    float* outY  = out;
    float* outHn = out + (size_t)BB * SS * HH;
    float* outCn = outHn + (size_t)BB * HH;
    unsigned long long* Y0l = (unsigned long long*)Y0;   // 64 u64 per 256-unit row
    unsigned long long* Y1l = (unsigned long long*)Y1;
    unsigned int* Y0u = (unsigned int*)Y0;
    unsigned int* Y1u = (unsigned int*)Y1;

    // ---- epoch-slot geometry: stride 32 u32 = 128B per slot ----
    unsigned int* slotsG0 = slots + (size_t)((0 * 8 + g) * 16) * 32;
    unsigned int* slotsG1 = slots + (size_t)((1 * 8 + g) * 16) * 32;
    unsigned int* myslot  = (LAYER ? slotsG1 : slotsG0) + s * 32;
    unsigned int* pollp;          // wave-0 per-lane poll target
    unsigned tgt_off;
    if (LAYER == 0) {
        pollp = slotsG0 + (L & 15) * 32;     // need peers' h0[t-1]: slot >= t
        tgt_off = 0u;
    } else {
        int idx = L & 31;                    // lanes 0-15: y0[t] (slot0 >= t+1)
        pollp = (idx < 16) ? (slotsG0 + idx * 32)
                           : (slotsG1 + (idx - 16) * 32);  // peers' h1[t-1]
        tgt_off = (idx < 16) ? 1u : 0u;
    }

    // staging geometry: one batch row per 8 threads, 8 x u64 per thread
    const int row8 = tid >> 3;        // 0..31
    const int c8   = tid & 7;         // u64 col base; cols c8 + 8j, j=0..7
    // x staging (layer0): float4 rows rowb+8k, col cc
    const int rowb = tid >> 5;
    const int cc   = tid & 31;

    for (int t = 0; t < SS; ++t) {
        unsigned long long yv[8];     // layer1: y0[t] staged regs
        float4 xv[4];                 // layer0: x[t]

        if (LAYER == 0) {
            // ---- prefetch x (no dependency) ----
#pragma unroll
            for (int k = 0; k < 4; ++k) {
                int row = rowb + 8 * k;
                xv[k] = *(const float4*)(x + ((size_t)(b0 + row) * SS + t) * II + cc * 4);
            }
            if (w == 0 && t > 0) {
                if (!wait_slots(pollp, (unsigned)t) && L == 0) *abort_flag = 1;
            }
            __syncthreads();
            if (*abort_flag) return;
        } else {
            // ---- combined wait: y0[t] ready AND peers' h1[t-1] ready ----
            if (w == 0) {
                unsigned tgt = (unsigned)t + tgt_off;   // t=0: h1 lanes auto-pass
                if (!wait_slots(pollp, tgt) && L == 0) *abort_flag = 1;
            }
            __syncthreads();
            if (*abort_flag) return;
            // ---- y0[t] loads (overlap with h1 gather below) ----
            {
                unsigned long long* sp = Y0l + ((size_t)t * BB + b0 + row8) * 64;
#pragma unroll
                for (int j = 0; j < 8; ++j)
                    yv[j] = __hip_atomic_load(sp + c8 + 8 * j, __ATOMIC_RELAXED,
                                              __HIP_MEMORY_SCOPE_AGENT);
            }
        }

        // ---- h_{t-1} gather (batched u64 agent atomics) ----
        unsigned long long hv[8];
        if (t > 0) {
            unsigned long long* sp = (LAYER == 0)
                ? Y0l + ((size_t)(t - 1) * BB + b0 + row8) * 64
                : Y1l + ((size_t)((t - 1) & 3) * BB + b0 + row8) * 64;
#pragma unroll
            for (int j = 0; j < 8; ++j)
                hv[j] = __hip_atomic_load(sp + c8 + 8 * j, __ATOMIC_RELAXED,
                                          __HIP_MEMORY_SCOPE_AGENT);
        } else {
#pragma unroll
            for (int j = 0; j < 8; ++j) hv[j] = 0ull;
        }

        // ---- write A = [input | h_prev] to LDS ----
        if (LAYER == 0) {
#pragma unroll
            for (int k = 0; k < 4; ++k) {
                int row = rowb + 8 * k;
                ushort4 pk;
                pk.x = f2bf(xv[k].x); pk.y = f2bf(xv[k].y);
                pk.z = f2bf(xv[k].z); pk.w = f2bf(xv[k].w);
                *(ushort4*)&As[row * KCP + cc * 4] = pk;
            }
        } else {
#pragma unroll
            for (int j = 0; j < 8; ++j)
                *(unsigned long long*)&As[row8 * KCP + (c8 + 8 * j) * 4] = yv[j];
        }
#pragma unroll
        for (int j = 0; j < 8; ++j)
            *(unsigned long long*)&As[row8 * KCP + KIN + (c8 + 8 * j) * 4] = hv[j];
        __syncthreads();

        // ---- GEMM: gates[32 x 64] = A[32 x KC] * W^T ----
        f32x4 acc0 = {0.f, 0.f, 0.f, 0.f};
        f32x4 acc1 = {0.f, 0.f, 0.f, 0.f};
        const unsigned short* aBase = &As[(mw * 16 + c) * KCP + (L >> 4) * 8];
#pragma unroll
        for (int kc = 0; kc < NKC; ++kc) {
            bf16x8 a = *(const bf16x8*)(aBase + kc * 32);
            acc0 = __builtin_amdgcn_mfma_f32_16x16x32_bf16(a, w0r[kc], acc0, 0, 0, 0);
            acc1 = __builtin_amdgcn_mfma_f32_16x16x32_bf16(a, w1r[kc], acc1, 0, 0, 0);
        }

        // ---- epilogue: acc0 = i|f, acc1 = g|o (partner lane L^8) ----
#pragma unroll
        for (int r = 0; r < 4; ++r) {
            float x0 = acc0[r] + bq0;
            float x1 = acc1[r] + bq1;
            float y0v = __shfl_xor(x0, 8, 64);
            float y1v = __shfl_xor(x1, 8, 64);
            bool lo = (L & 8) == 0;
            float iv = lo ? x0 : y0v;
            float fv = lo ? y0v : x0;
            float gv = lo ? x1 : y1v;
            float ov = lo ? y1v : x1;
            iv = 1.f / (1.f + __expf(-iv));
            fv = 1.f / (1.f + __expf(-fv));
            ov = 1.f / (1.f + __expf(-ov));
            gv = 1.f - 2.f / (1.f + __expf(2.f * gv));
            float cn = fv * cst[r] + iv * gv;
            cst[r] = cn;
            float tc = 1.f - 2.f / (1.f + __expf(2.f * cn));
            float hn = ov * tc;

            int brow = b0 + mw * 16 + ((L >> 4) << 2) + r;
            int hu = s * 16 + nwv * 8 + (L & 7);
            // pack 2 adjacent units (lane pair L, L^1) into one 4B RETURNING
            // far-atomic swap (R5-proven: vmcnt retires only on LLC reply).
            unsigned hb = (unsigned)f2bf(hn);
            unsigned pb = (unsigned)__shfl_xor((int)hb, 1, 64);
            unsigned packed = hb | (pb << 16);
            if (lo && (L & 1) == 0) {
                size_t di = (((size_t)(LAYER == 0 ? t * BB : (size_t)(t & 3) * BB)
                              + brow) * HH + hu) >> 1;
                unsigned old = __hip_atomic_exchange(
                    (LAYER == 0 ? Y0u : Y1u) + di, packed,
                    __ATOMIC_RELAXED, __HIP_MEMORY_SCOPE_AGENT);
                asm volatile("" :: "v"(old));   // keep returning form; no cost
            }
            if (LAYER == 1 && lo) {
                outY[((size_t)brow * SS + t) * HH + hu] = hn;
                if (t == SS - 1) {
                    outHn[brow * HH + hu] = hn;
                    outCn[brow * HH + hu] = cn;
                }
            }
        }

        __syncthreads();  // vmcnt(0): all returning swaps ack'd BY THE LLC
        if (tid == 0) {
            // own-line epoch publish: no RMW contention, data already at LLC
            unsigned old = __hip_atomic_exchange(myslot, (unsigned)(t + 1),
                                                 __ATOMIC_RELAXED,
                                                 __HIP_MEMORY_SCOPE_AGENT);
            asm volatile("" :: "v"(old));
        }
    }
}

__global__ __launch_bounds__(256, 1) void lstm_main(
    const float* __restrict__ x,
    const unsigned short* __restrict__ wp0,
    const unsigned short* __restrict__ wp1,
    const float* __restrict__ biasP,
    unsigned short* __restrict__ Y0,
    unsigned short* __restrict__ Y1,
    unsigned int* __restrict__ slots,
    float* __restrict__ out) {

    __shared__ unsigned short As[32 * 520];
    __shared__ int abort_flag;
    if (threadIdx.x == 0) abort_flag = 0;

    int bid = blockIdx.x;
    if (bid < 128)
        run_layer<0>(bid, x, wp0, biasP, Y0, Y1, slots, out, As, &abort_flag);
    else
        run_layer<1>(bid, x, wp1, biasP, Y0, Y1, slots, out, As, &abort_flag);
}

extern "C" void kernel_launch(void* const* d_in, const int* in_sizes, int n_in,
                              void* d_out, int out_size, void* d_ws, size_t ws_size,
                              hipStream_t stream) {
    const float* x    = (const float*)d_in[0];
    const float* Wih0 = (const float*)d_in[1];
    const float* Whh0 = (const float*)d_in[2];
    const float* bih0 = (const float*)d_in[3];
    const float* bhh0 = (const float*)d_in[4];
    const float* Wih1 = (const float*)d_in[5];
    const float* Whh1 = (const float*)d_in[6];
    const float* bih1 = (const float*)d_in[7];
    const float* bhh1 = (const float*)d_in[8];

    char* ws = (char*)d_ws;
    size_t o = 0;
    unsigned short* wp0 = (unsigned short*)(ws + o); o += (size_t)64 * 12 * 512 * 2;  // 768 KB
    unsigned short* wp1 = (unsigned short*)(ws + o); o += (size_t)64 * 16 * 512 * 2;  // 1 MB
    float* biasP = (float*)(ws + o);                 o += 2048 * 4;
    unsigned short* Y0 = (unsigned short*)(ws + o);  o += (size_t)SS * BB * HH * 2;   // 67 MB
    unsigned short* Y1 = (unsigned short*)(ws + o);  o += (size_t)4 * BB * HH * 2;    // 512 KB
    unsigned int* slots = (unsigned int*)(ws + o);   o += (size_t)2 * 8 * 16 * 32 * 4; // 16 KB

    hipMemsetAsync(slots, 0, (size_t)2 * 8 * 16 * 32 * 4, stream);
    pack_w_kernel<<<192, 256, 0, stream>>>(Wih0, Whh0, wp0, II, 12);
    pack_w_kernel<<<256, 256, 0, stream>>>(Wih1, Whh1, wp1, HH, 16);
    pack_bias_kernel<<<8, 256, 0, stream>>>(bih0, bhh0, bih1, bhh1, biasP);
    lstm_main<<<256, 256, 0, stream>>>(x, wp0, wp1, biasP, Y0, Y1, slots, (float*)d_out);
}